// Round 1
// baseline (951.645 us; speedup 1.0000x reference)
//
#include <hip/hip_runtime.h>
#include <hip/hip_bf16.h>

// ---------------------------------------------------------------------------
// TAGConv x2 (K=3) on N=50000 nodes, E=800000 edges, 128->128 relu ->40 logsoftmax
// Strategy:
//   norm_e = dis[src]*w*dis[dst], dis = rsqrt(deg by dst)
//   Build dst-grouped CSR on device (counts -> scan -> scatter) to avoid
//   400M float atomics in propagation.
//   Horner: out = y0 + A(y1 + A(y2 + A y3)),  y_k = X @ W[k]
//   Layer2 propagates 40-wide (A commutes with right-multiply by W).
// ---------------------------------------------------------------------------

__global__ void zero_kernel(float* __restrict__ deg, int* __restrict__ cnt, int n) {
  int i = blockIdx.x * blockDim.x + threadIdx.x;
  if (i < n) { deg[i] = 0.f; cnt[i] = 0; }
}

__global__ void count_kernel(const int* __restrict__ ei, const float* __restrict__ ew,
                             float* __restrict__ deg, int* __restrict__ cnt, int E) {
  int e = blockIdx.x * blockDim.x + threadIdx.x;
  if (e < E) {
    int d = ei[E + e];          // edge_index[1][e] = dst
    atomicAdd(&deg[d], ew[e]);
    atomicAdd(&cnt[d], 1);
  }
}

__global__ void rsqrt_kernel(float* __restrict__ deg, int n) {
  int i = blockIdx.x * blockDim.x + threadIdx.x;
  if (i < n) { float d = deg[i]; deg[i] = (d > 0.f) ? rsqrtf(d) : 0.f; }
}

// exclusive scan of cnt[0..n) -> rowptr[0..n], single block of 1024 threads
__global__ __launch_bounds__(1024) void scan_kernel(const int* __restrict__ cnt,
                                                    int* __restrict__ rowptr, int n) {
  __shared__ int warp_sums[16];
  __shared__ int carry_s;
  int lane = threadIdx.x & 63;
  int wid  = threadIdx.x >> 6;
  if (threadIdx.x == 0) carry_s = 0;
  __syncthreads();
  for (int base = 0; base < n; base += 1024) {
    int i = base + (int)threadIdx.x;
    int v = (i < n) ? cnt[i] : 0;
    int sv = v;
    #pragma unroll
    for (int off = 1; off < 64; off <<= 1) {
      int t = __shfl_up(sv, off);
      if (lane >= off) sv += t;
    }
    if (lane == 63) warp_sums[wid] = sv;
    __syncthreads();
    if (wid == 0) {
      int ws = (lane < 16) ? warp_sums[lane] : 0;
      #pragma unroll
      for (int off = 1; off < 16; off <<= 1) {
        int t = __shfl_up(ws, off);
        if (lane >= off) ws += t;
      }
      if (lane < 16) warp_sums[lane] = ws;
    }
    __syncthreads();
    int carry = carry_s;
    int wprefix = (wid > 0) ? warp_sums[wid - 1] : 0;
    int incl = sv + wprefix + carry;
    if (i < n) rowptr[i + 1] = incl;
    __syncthreads();
    if (threadIdx.x == 1023) carry_s = incl;  // chunk total (padding adds 0)
    __syncthreads();
  }
  if (threadIdx.x == 0) rowptr[0] = 0;
}

__global__ void copy_kernel(const int* __restrict__ rowptr, int* __restrict__ cursor, int n) {
  int i = blockIdx.x * blockDim.x + threadIdx.x;
  if (i < n) cursor[i] = rowptr[i];
}

__global__ void scatter_kernel(const int* __restrict__ ei, const float* __restrict__ ew,
                               const float* __restrict__ dis, int* __restrict__ cursor,
                               int* __restrict__ src_s, float* __restrict__ w_s, int E) {
  int e = blockIdx.x * blockDim.x + threadIdx.x;
  if (e < E) {
    int s = ei[e];
    int d = ei[E + e];
    float nw = dis[s] * ew[e] * dis[d];
    int pos = atomicAdd(&cursor[d], 1);
    src_s[pos] = s;
    w_s[pos]   = nw;
  }
}

// Y[n x 128] (+)= X[n x 128] @ W[128 x 128]; 32 rows per block
__global__ __launch_bounds__(256) void gemm128_kernel(const float* __restrict__ X,
                                                      const float* __restrict__ W,
                                                      float* __restrict__ Y, int n, int doacc) {
  __shared__ float sW[128 * 128];   // 64 KiB
  __shared__ float sX[32 * 128];    // 16 KiB
  int t = threadIdx.x;
  for (int i = t * 4; i < 128 * 128; i += 1024)
    *(float4*)&sW[i] = *(const float4*)&W[i];
  int row0 = blockIdx.x * 32;
  for (int i = t * 4; i < 32 * 128; i += 1024) {
    int r = row0 + (i >> 7);
    float4 v = make_float4(0.f, 0.f, 0.f, 0.f);
    if (r < n) v = *(const float4*)&X[r * 128 + (i & 127)];
    *(float4*)&sX[i] = v;
  }
  __syncthreads();
  int tx = t & 31;   // col group: cols tx*4 .. tx*4+3
  int ty = t >> 5;   // row group: rows ty*4 .. ty*4+3
  float a[4][4];
  #pragma unroll
  for (int i = 0; i < 4; ++i)
    #pragma unroll
    for (int j = 0; j < 4; ++j) a[i][j] = 0.f;
  for (int k = 0; k < 128; ++k) {
    float4 w4 = *(const float4*)&sW[k * 128 + tx * 4];
    #pragma unroll
    for (int i = 0; i < 4; ++i) {
      float xv = sX[(ty * 4 + i) * 128 + k];
      a[i][0] += xv * w4.x; a[i][1] += xv * w4.y;
      a[i][2] += xv * w4.z; a[i][3] += xv * w4.w;
    }
  }
  #pragma unroll
  for (int i = 0; i < 4; ++i) {
    int r = row0 + ty * 4 + i;
    if (r < n) {
      float4* yp = (float4*)&Y[r * 128 + tx * 4];
      float4 v = make_float4(a[i][0], a[i][1], a[i][2], a[i][3]);
      if (doacc) { float4 o = *yp; v.x += o.x; v.y += o.y; v.z += o.z; v.w += o.w; }
      *yp = v;
    }
  }
}

// Y[n x 40] (+)= X[n x 128] @ W[128 x 40]; 32 rows per block, 320 threads
__global__ __launch_bounds__(320) void gemm40_kernel(const float* __restrict__ X,
                                                     const float* __restrict__ W,
                                                     float* __restrict__ Y, int n, int doacc) {
  __shared__ float sW[128 * 40];    // 20 KiB
  __shared__ float sX[32 * 128];    // 16 KiB
  int t = threadIdx.x;
  for (int i = t * 4; i < 128 * 40; i += 1280)
    *(float4*)&sW[i] = *(const float4*)&W[i];
  int row0 = blockIdx.x * 32;
  for (int i = t * 4; i < 32 * 128; i += 1280) {
    int r = row0 + (i >> 7);
    float4 v = make_float4(0.f, 0.f, 0.f, 0.f);
    if (r < n) v = *(const float4*)&X[r * 128 + (i & 127)];
    *(float4*)&sX[i] = v;
  }
  __syncthreads();
  int col = t % 40, slot = t / 40;   // slot 0..7, 4 rows each
  float a0 = 0.f, a1 = 0.f, a2 = 0.f, a3 = 0.f;
  for (int k = 0; k < 128; ++k) {
    float wv = sW[k * 40 + col];
    a0 += sX[(slot * 4 + 0) * 128 + k] * wv;
    a1 += sX[(slot * 4 + 1) * 128 + k] * wv;
    a2 += sX[(slot * 4 + 2) * 128 + k] * wv;
    a3 += sX[(slot * 4 + 3) * 128 + k] * wv;
  }
  float acc[4] = {a0, a1, a2, a3};
  #pragma unroll
  for (int i = 0; i < 4; ++i) {
    int r = row0 + slot * 4 + i;
    if (r < n) {
      float v = acc[i];
      if (doacc) v += Y[r * 40 + col];
      Y[r * 40 + col] = v;
    }
  }
}

// dst[n x 128] = A_norm . src_feat ; one wave per node, lane handles float2
__global__ __launch_bounds__(256) void prop128_kernel(const float* __restrict__ src_feat,
                                                      float* __restrict__ dstf,
                                                      const int* __restrict__ rowptr,
                                                      const int* __restrict__ src_s,
                                                      const float* __restrict__ w_s, int n) {
  int lane = threadIdx.x & 63;
  int node = blockIdx.x * 4 + (threadIdx.x >> 6);
  if (node >= n) return;
  int beg = rowptr[node], end = rowptr[node + 1];
  const float2* sf = (const float2*)src_feat;
  float2 acc = make_float2(0.f, 0.f);
  for (int e = beg; e < end; ++e) {
    int s    = src_s[e];
    float wt = w_s[e];
    float2 v = sf[s * 64 + lane];
    acc.x += wt * v.x;
    acc.y += wt * v.y;
  }
  ((float2*)dstf)[node * 64 + lane] = acc;
}

// dst[n x 40] = A_norm . src_feat ; one wave per node, lanes 0..39 active
__global__ __launch_bounds__(256) void prop40_kernel(const float* __restrict__ src_feat,
                                                     float* __restrict__ dstf,
                                                     const int* __restrict__ rowptr,
                                                     const int* __restrict__ src_s,
                                                     const float* __restrict__ w_s, int n) {
  int lane = threadIdx.x & 63;
  int node = blockIdx.x * 4 + (threadIdx.x >> 6);
  if (node >= n) return;
  int beg = rowptr[node], end = rowptr[node + 1];
  float acc = 0.f;
  for (int e = beg; e < end; ++e) {
    int s    = src_s[e];
    float wt = w_s[e];
    float v  = (lane < 40) ? src_feat[s * 40 + lane] : 0.f;
    acc += wt * v;
  }
  if (lane < 40) dstf[node * 40 + lane] = acc;
}

__global__ void bias_relu_kernel(float* __restrict__ T, const float* __restrict__ b, int total) {
  int i = blockIdx.x * blockDim.x + threadIdx.x;
  if (i < total) {
    float v = T[i] + b[i & 127];
    T[i] = (v > 0.f) ? v : 0.f;
  }
}

// out[n x 40] = log_softmax(Z + b2); one wave per node
__global__ __launch_bounds__(256) void lsm_kernel(const float* __restrict__ Z,
                                                  const float* __restrict__ b,
                                                  float* __restrict__ out, int n) {
  int lane = threadIdx.x & 63;
  int node = blockIdx.x * 4 + (threadIdx.x >> 6);
  if (node >= n) return;
  float v = -1e30f;
  if (lane < 40) v = Z[node * 40 + lane] + b[lane];
  float m = v;
  #pragma unroll
  for (int off = 32; off; off >>= 1) m = fmaxf(m, __shfl_xor(m, off));
  float ex = (lane < 40) ? __expf(v - m) : 0.f;
  float s = ex;
  #pragma unroll
  for (int off = 32; off; off >>= 1) s += __shfl_xor(s, off);
  if (lane < 40) out[node * 40 + lane] = v - m - __logf(s);
}

extern "C" void kernel_launch(void* const* d_in, const int* in_sizes, int n_in,
                              void* d_out, int out_size, void* d_ws, size_t ws_size,
                              hipStream_t stream) {
  const float* x  = (const float*)d_in[0];
  const int*   ei = (const int*)d_in[1];
  const float* ew = (const float*)d_in[2];
  const float* W1 = (const float*)d_in[3];
  const float* b1 = (const float*)d_in[4];
  const float* W2 = (const float*)d_in[5];
  const float* b2 = (const float*)d_in[6];
  float* out = (float*)d_out;

  const int N = in_sizes[0] / 128;   // 50000
  const int E = in_sizes[2];         // 800000

  char* ws = (char*)d_ws;
  size_t off = 0;
  auto alloc = [&](size_t bytes) -> void* {
    off = (off + 255) & ~(size_t)255;
    void* p = ws + off;
    off += bytes;
    return p;
  };
  float* deg    = (float*)alloc((size_t)N * 4);          // becomes dis after rsqrt
  int*   rowptr = (int*)  alloc((size_t)(N + 1) * 4);
  int*   cursor = (int*)  alloc((size_t)N * 4);          // counts, then cursors
  int*   src_s  = (int*)  alloc((size_t)E * 4);
  float* w_s    = (float*)alloc((size_t)E * 4);
  float* tA     = (float*)alloc((size_t)N * 128 * 4);
  float* tB     = (float*)alloc((size_t)N * 128 * 4);
  float* zA     = tA;                    // N*40 each, alias into tA region
  float* zB     = tA + (size_t)N * 40;
  (void)ws_size; (void)n_in; (void)out_size;

  int nb_n = (N + 255) / 256;
  int nb_e = (E + 255) / 256;
  int nb_g = (N + 31) / 32;
  int nb_p = (N + 3) / 4;
  int nb_r = (N * 128 + 255) / 256;

  // ---- graph preprocessing: norm + dst-CSR ----
  zero_kernel<<<nb_n, 256, 0, stream>>>(deg, cursor, N);
  count_kernel<<<nb_e, 256, 0, stream>>>(ei, ew, deg, cursor, E);
  rsqrt_kernel<<<nb_n, 256, 0, stream>>>(deg, N);
  scan_kernel<<<1, 1024, 0, stream>>>(cursor, rowptr, N);
  copy_kernel<<<nb_n, 256, 0, stream>>>(rowptr, cursor, N);
  scatter_kernel<<<nb_e, 256, 0, stream>>>(ei, ew, deg, cursor, src_s, w_s, E);

  // ---- layer 1 (Horner): tB = y0 + A(y1 + A(y2 + A y3)), y_k = x @ W1[k] ----
  gemm128_kernel<<<nb_g, 256, 0, stream>>>(x, W1 + 3 * 16384, tA, N, 0);
  prop128_kernel<<<nb_p, 256, 0, stream>>>(tA, tB, rowptr, src_s, w_s, N);
  gemm128_kernel<<<nb_g, 256, 0, stream>>>(x, W1 + 2 * 16384, tB, N, 1);
  prop128_kernel<<<nb_p, 256, 0, stream>>>(tB, tA, rowptr, src_s, w_s, N);
  gemm128_kernel<<<nb_g, 256, 0, stream>>>(x, W1 + 1 * 16384, tA, N, 1);
  prop128_kernel<<<nb_p, 256, 0, stream>>>(tA, tB, rowptr, src_s, w_s, N);
  gemm128_kernel<<<nb_g, 256, 0, stream>>>(x, W1 + 0 * 16384, tB, N, 1);
  bias_relu_kernel<<<nb_r, 256, 0, stream>>>(tB, b1, N * 128);   // h = tB

  // ---- layer 2 (Horner, 40-wide propagation) ----
  gemm40_kernel<<<nb_g, 320, 0, stream>>>(tB, W2 + 3 * 5120, zA, N, 0);
  prop40_kernel<<<nb_p, 256, 0, stream>>>(zA, zB, rowptr, src_s, w_s, N);
  gemm40_kernel<<<nb_g, 320, 0, stream>>>(tB, W2 + 2 * 5120, zB, N, 1);
  prop40_kernel<<<nb_p, 256, 0, stream>>>(zB, zA, rowptr, src_s, w_s, N);
  gemm40_kernel<<<nb_g, 320, 0, stream>>>(tB, W2 + 1 * 5120, zA, N, 1);
  prop40_kernel<<<nb_p, 256, 0, stream>>>(zA, zB, rowptr, src_s, w_s, N);
  gemm40_kernel<<<nb_g, 320, 0, stream>>>(tB, W2 + 0 * 5120, zB, N, 1);

  // ---- log_softmax ----
  lsm_kernel<<<nb_p, 256, 0, stream>>>(zB, b2, out, N);
}

// Round 2
// 717.850 us; speedup vs baseline: 1.3257x; 1.3257x over previous
//
#include <hip/hip_runtime.h>
#include <hip/hip_bf16.h>
#include <hip/hip_fp16.h>

// ---------------------------------------------------------------------------
// TAGConv x2 (K=3), N=50000, E=800000, 128->128 relu -> 40 logsoftmax
//   Horner: out = y0 + A(y1 + A(y2 + A y3)), y_k = X @ W[k]
//   dst-grouped CSR built on device; edges packed as int2{src, w_bits}.
//   Layer-1 propagation gathers fp16 (GEMM epilogue emits fp16 only;
//   fp32 accumulate everywhere). Layer-2 propagation fp32 (40-wide).
// ---------------------------------------------------------------------------

__global__ void zero_kernel(float* __restrict__ deg, int* __restrict__ cnt, int n) {
  int i = blockIdx.x * blockDim.x + threadIdx.x;
  if (i < n) { deg[i] = 0.f; cnt[i] = 0; }
}

__global__ void count_kernel(const int* __restrict__ ei, const float* __restrict__ ew,
                             float* __restrict__ deg, int* __restrict__ cnt, int E) {
  int e = blockIdx.x * blockDim.x + threadIdx.x;
  if (e < E) {
    int d = ei[E + e];          // dst
    atomicAdd(&deg[d], ew[e]);
    atomicAdd(&cnt[d], 1);
  }
}

__global__ void rsqrt_kernel(float* __restrict__ deg, int n) {
  int i = blockIdx.x * blockDim.x + threadIdx.x;
  if (i < n) { float d = deg[i]; deg[i] = (d > 0.f) ? rsqrtf(d) : 0.f; }
}

// exclusive scan of cnt[0..n) -> rowptr[0..n], single block of 1024 threads
__global__ __launch_bounds__(1024) void scan_kernel(const int* __restrict__ cnt,
                                                    int* __restrict__ rowptr, int n) {
  __shared__ int warp_sums[16];
  __shared__ int carry_s;
  int lane = threadIdx.x & 63;
  int wid  = threadIdx.x >> 6;
  if (threadIdx.x == 0) carry_s = 0;
  __syncthreads();
  for (int base = 0; base < n; base += 1024) {
    int i = base + (int)threadIdx.x;
    int v = (i < n) ? cnt[i] : 0;
    int sv = v;
    #pragma unroll
    for (int off = 1; off < 64; off <<= 1) {
      int t = __shfl_up(sv, off);
      if (lane >= off) sv += t;
    }
    if (lane == 63) warp_sums[wid] = sv;
    __syncthreads();
    if (wid == 0) {
      int ws = (lane < 16) ? warp_sums[lane] : 0;
      #pragma unroll
      for (int off = 1; off < 16; off <<= 1) {
        int t = __shfl_up(ws, off);
        if (lane >= off) ws += t;
      }
      if (lane < 16) warp_sums[lane] = ws;
    }
    __syncthreads();
    int carry = carry_s;
    int wprefix = (wid > 0) ? warp_sums[wid - 1] : 0;
    int incl = sv + wprefix + carry;
    if (i < n) rowptr[i + 1] = incl;
    __syncthreads();
    if (threadIdx.x == 1023) carry_s = incl;
    __syncthreads();
  }
  if (threadIdx.x == 0) rowptr[0] = 0;
}

__global__ void copy_kernel(const int* __restrict__ rowptr, int* __restrict__ cursor, int n) {
  int i = blockIdx.x * blockDim.x + threadIdx.x;
  if (i < n) cursor[i] = rowptr[i];
}

__global__ void scatter_kernel(const int* __restrict__ ei, const float* __restrict__ ew,
                               const float* __restrict__ dis, int* __restrict__ cursor,
                               int2* __restrict__ es, int E) {
  int e = blockIdx.x * blockDim.x + threadIdx.x;
  if (e < E) {
    int s = ei[e];
    int d = ei[E + e];
    float nw = dis[s] * ew[e] * dis[d];
    int pos = atomicAdd(&cursor[d], 1);
    es[pos] = make_int2(s, __float_as_int(nw));
  }
}

// Yh[n x 128](fp16) = relu?( Acc? + X @ W + bias? ) ; 32 rows/block
__global__ __launch_bounds__(256) void gemm128_kernel(const float* __restrict__ X,
                                                      const float* __restrict__ W,
                                                      const float* __restrict__ Acc,
                                                      const float* __restrict__ bias,
                                                      __half* __restrict__ Yh, int n) {
  __shared__ float sW[128 * 128];   // 64 KiB
  __shared__ float sX[32 * 128];    // 16 KiB
  int t = threadIdx.x;
  for (int i = t * 4; i < 128 * 128; i += 1024)
    *(float4*)&sW[i] = *(const float4*)&W[i];
  int row0 = blockIdx.x * 32;
  for (int i = t * 4; i < 32 * 128; i += 1024) {
    int r = row0 + (i >> 7);
    float4 v = make_float4(0.f, 0.f, 0.f, 0.f);
    if (r < n) v = *(const float4*)&X[r * 128 + (i & 127)];
    *(float4*)&sX[i] = v;
  }
  __syncthreads();
  int tx = t & 31;   // cols tx*4..tx*4+3
  int ty = t >> 5;   // rows ty*4..ty*4+3
  float a[4][4];
  #pragma unroll
  for (int i = 0; i < 4; ++i)
    #pragma unroll
    for (int j = 0; j < 4; ++j) a[i][j] = 0.f;
  for (int k = 0; k < 128; ++k) {
    float4 w4 = *(const float4*)&sW[k * 128 + tx * 4];
    #pragma unroll
    for (int i = 0; i < 4; ++i) {
      float xv = sX[(ty * 4 + i) * 128 + k];
      a[i][0] += xv * w4.x; a[i][1] += xv * w4.y;
      a[i][2] += xv * w4.z; a[i][3] += xv * w4.w;
    }
  }
  #pragma unroll
  for (int i = 0; i < 4; ++i) {
    int r = row0 + ty * 4 + i;
    if (r < n) {
      float4 v = make_float4(a[i][0], a[i][1], a[i][2], a[i][3]);
      if (Acc) {
        float4 o = *(const float4*)&Acc[r * 128 + tx * 4];
        v.x += o.x; v.y += o.y; v.z += o.z; v.w += o.w;
      }
      if (bias) {
        v.x = fmaxf(v.x + bias[tx * 4 + 0], 0.f);
        v.y = fmaxf(v.y + bias[tx * 4 + 1], 0.f);
        v.z = fmaxf(v.z + bias[tx * 4 + 2], 0.f);
        v.w = fmaxf(v.w + bias[tx * 4 + 3], 0.f);
      }
      __half2 h01 = __floats2half2_rn(v.x, v.y);
      __half2 h23 = __floats2half2_rn(v.z, v.w);
      __half2* yp = (__half2*)&Yh[r * 128 + tx * 4];
      yp[0] = h01; yp[1] = h23;
    }
  }
}

// Y[n x 40](fp32) = Acc? + Xh(fp16) @ W ; 32 rows/block, 320 threads
__global__ __launch_bounds__(320) void gemm40_kernel(const __half* __restrict__ Xh,
                                                     const float* __restrict__ W,
                                                     const float* __restrict__ Acc,
                                                     float* __restrict__ Y, int n) {
  __shared__ float sW[128 * 40];    // 20 KiB
  __shared__ float sX[32 * 128];    // 16 KiB
  int t = threadIdx.x;
  for (int i = t * 4; i < 128 * 40; i += 1280)
    *(float4*)&sW[i] = *(const float4*)&W[i];
  int row0 = blockIdx.x * 32;
  for (int i = t * 4; i < 32 * 128; i += 1280) {
    int r = row0 + (i >> 7);
    float4 v = make_float4(0.f, 0.f, 0.f, 0.f);
    if (r < n) {
      const __half2* xp = (const __half2*)&Xh[r * 128 + (i & 127)];
      float2 f0 = __half22float2(xp[0]);
      float2 f1 = __half22float2(xp[1]);
      v = make_float4(f0.x, f0.y, f1.x, f1.y);
    }
    *(float4*)&sX[i] = v;
  }
  __syncthreads();
  int col = t % 40, slot = t / 40;   // slot 0..7, 4 rows each
  float a0 = 0.f, a1 = 0.f, a2 = 0.f, a3 = 0.f;
  for (int k = 0; k < 128; ++k) {
    float wv = sW[k * 40 + col];
    a0 += sX[(slot * 4 + 0) * 128 + k] * wv;
    a1 += sX[(slot * 4 + 1) * 128 + k] * wv;
    a2 += sX[(slot * 4 + 2) * 128 + k] * wv;
    a3 += sX[(slot * 4 + 3) * 128 + k] * wv;
  }
  float acc[4] = {a0, a1, a2, a3};
  #pragma unroll
  for (int i = 0; i < 4; ++i) {
    int r = row0 + slot * 4 + i;
    if (r < n) {
      float v = acc[i];
      if (Acc) v += Acc[r * 40 + col];
      Y[r * 40 + col] = v;
    }
  }
}

// P[n x 128](fp32) = A_norm . srch(fp16) ; one wave/node, lane = half2 (4B)
__global__ __launch_bounds__(256) void prop128_kernel(const __half* __restrict__ srch,
                                                      float* __restrict__ dstf,
                                                      const int* __restrict__ rowptr,
                                                      const int2* __restrict__ es, int n) {
  int lane = threadIdx.x & 63;
  int node = blockIdx.x * 4 + (threadIdx.x >> 6);
  if (node >= n) return;
  int beg = rowptr[node], end = rowptr[node + 1];
  const __half2* sf = (const __half2*)srch;
  float ax = 0.f, ay = 0.f;
  int e = beg;
  for (; e + 3 < end; e += 4) {
    int2 p0 = es[e], p1 = es[e + 1], p2 = es[e + 2], p3 = es[e + 3];
    float2 v0 = __half22float2(sf[(size_t)p0.x * 64 + lane]);
    float2 v1 = __half22float2(sf[(size_t)p1.x * 64 + lane]);
    float2 v2 = __half22float2(sf[(size_t)p2.x * 64 + lane]);
    float2 v3 = __half22float2(sf[(size_t)p3.x * 64 + lane]);
    float w0 = __int_as_float(p0.y), w1 = __int_as_float(p1.y);
    float w2 = __int_as_float(p2.y), w3 = __int_as_float(p3.y);
    ax += w0 * v0.x; ay += w0 * v0.y;
    ax += w1 * v1.x; ay += w1 * v1.y;
    ax += w2 * v2.x; ay += w2 * v2.y;
    ax += w3 * v3.x; ay += w3 * v3.y;
  }
  for (; e < end; ++e) {
    int2 p = es[e];
    float2 v = __half22float2(sf[(size_t)p.x * 64 + lane]);
    float w = __int_as_float(p.y);
    ax += w * v.x; ay += w * v.y;
  }
  ((float2*)dstf)[node * 64 + lane] = make_float2(ax, ay);
}

// Z[n x 40](fp32) = A_norm . src(fp32) ; one wave/node, lanes 0..39
__global__ __launch_bounds__(256) void prop40_kernel(const float* __restrict__ src_feat,
                                                     float* __restrict__ dstf,
                                                     const int* __restrict__ rowptr,
                                                     const int2* __restrict__ es, int n) {
  int lane = threadIdx.x & 63;
  int node = blockIdx.x * 4 + (threadIdx.x >> 6);
  if (node >= n) return;
  int beg = rowptr[node], end = rowptr[node + 1];
  float acc = 0.f;
  int e = beg;
  for (; e + 3 < end; e += 4) {
    int2 p0 = es[e], p1 = es[e + 1], p2 = es[e + 2], p3 = es[e + 3];
    float v0 = (lane < 40) ? src_feat[(size_t)p0.x * 40 + lane] : 0.f;
    float v1 = (lane < 40) ? src_feat[(size_t)p1.x * 40 + lane] : 0.f;
    float v2 = (lane < 40) ? src_feat[(size_t)p2.x * 40 + lane] : 0.f;
    float v3 = (lane < 40) ? src_feat[(size_t)p3.x * 40 + lane] : 0.f;
    acc += __int_as_float(p0.y) * v0 + __int_as_float(p1.y) * v1
         + __int_as_float(p2.y) * v2 + __int_as_float(p3.y) * v3;
  }
  for (; e < end; ++e) {
    int2 p = es[e];
    float v = (lane < 40) ? src_feat[(size_t)p.x * 40 + lane] : 0.f;
    acc += __int_as_float(p.y) * v;
  }
  if (lane < 40) dstf[node * 40 + lane] = acc;
}

// out[n x 40] = log_softmax(Z + b2); one wave per node
__global__ __launch_bounds__(256) void lsm_kernel(const float* __restrict__ Z,
                                                  const float* __restrict__ b,
                                                  float* __restrict__ out, int n) {
  int lane = threadIdx.x & 63;
  int node = blockIdx.x * 4 + (threadIdx.x >> 6);
  if (node >= n) return;
  float v = -1e30f;
  if (lane < 40) v = Z[node * 40 + lane] + b[lane];
  float m = v;
  #pragma unroll
  for (int off = 32; off; off >>= 1) m = fmaxf(m, __shfl_xor(m, off));
  float ex = (lane < 40) ? __expf(v - m) : 0.f;
  float s = ex;
  #pragma unroll
  for (int off = 32; off; off >>= 1) s += __shfl_xor(s, off);
  if (lane < 40) out[node * 40 + lane] = v - m - __logf(s);
}

extern "C" void kernel_launch(void* const* d_in, const int* in_sizes, int n_in,
                              void* d_out, int out_size, void* d_ws, size_t ws_size,
                              hipStream_t stream) {
  const float* x  = (const float*)d_in[0];
  const int*   ei = (const int*)d_in[1];
  const float* ew = (const float*)d_in[2];
  const float* W1 = (const float*)d_in[3];
  const float* b1 = (const float*)d_in[4];
  const float* W2 = (const float*)d_in[5];
  const float* b2 = (const float*)d_in[6];
  float* out = (float*)d_out;

  const int N = in_sizes[0] / 128;   // 50000
  const int E = in_sizes[2];         // 800000

  char* ws = (char*)d_ws;
  size_t off = 0;
  auto alloc = [&](size_t bytes) -> void* {
    off = (off + 255) & ~(size_t)255;
    void* p = ws + off;
    off += bytes;
    return p;
  };
  float*  deg    = (float*) alloc((size_t)N * 4);
  int*    rowptr = (int*)   alloc((size_t)(N + 1) * 4);
  int*    cursor = (int*)   alloc((size_t)N * 4);
  int2*   es     = (int2*)  alloc((size_t)E * 8);
  float*  P      = (float*) alloc((size_t)N * 128 * 4);  // prop output / gemm acc
  __half* Hh     = (__half*)alloc((size_t)N * 128 * 2);  // gemm fp16 output
  float*  zA     = (float*) alloc((size_t)N * 40 * 4);
  float*  zB     = (float*) alloc((size_t)N * 40 * 4);
  (void)ws_size; (void)n_in; (void)out_size; (void)ew;

  int nb_n = (N + 255) / 256;
  int nb_e = (E + 255) / 256;
  int nb_g = (N + 31) / 32;
  int nb_p = (N + 3) / 4;

  // ---- graph preprocessing: norm + dst-CSR ----
  zero_kernel<<<nb_n, 256, 0, stream>>>(deg, cursor, N);
  count_kernel<<<nb_e, 256, 0, stream>>>(ei, ew, deg, cursor, E);
  rsqrt_kernel<<<nb_n, 256, 0, stream>>>(deg, N);
  scan_kernel<<<1, 1024, 0, stream>>>(cursor, rowptr, N);
  copy_kernel<<<nb_n, 256, 0, stream>>>(rowptr, cursor, N);
  scatter_kernel<<<nb_e, 256, 0, stream>>>(ei, ew, deg, cursor, es, E);

  // ---- layer 1 (Horner, fp16 gathers) ----
  gemm128_kernel<<<nb_g, 256, 0, stream>>>(x, W1 + 3 * 16384, nullptr, nullptr, Hh, N);
  prop128_kernel<<<nb_p, 256, 0, stream>>>(Hh, P, rowptr, es, N);
  gemm128_kernel<<<nb_g, 256, 0, stream>>>(x, W1 + 2 * 16384, P, nullptr, Hh, N);
  prop128_kernel<<<nb_p, 256, 0, stream>>>(Hh, P, rowptr, es, N);
  gemm128_kernel<<<nb_g, 256, 0, stream>>>(x, W1 + 1 * 16384, P, nullptr, Hh, N);
  prop128_kernel<<<nb_p, 256, 0, stream>>>(Hh, P, rowptr, es, N);
  gemm128_kernel<<<nb_g, 256, 0, stream>>>(x, W1 + 0 * 16384, P, b1, Hh, N);  // h (fp16)

  // ---- layer 2 (Horner, 40-wide fp32 propagation) ----
  gemm40_kernel<<<nb_g, 320, 0, stream>>>(Hh, W2 + 3 * 5120, nullptr, zA, N);
  prop40_kernel<<<nb_p, 256, 0, stream>>>(zA, zB, rowptr, es, N);
  gemm40_kernel<<<nb_g, 320, 0, stream>>>(Hh, W2 + 2 * 5120, zB, zA, N);
  prop40_kernel<<<nb_p, 256, 0, stream>>>(zA, zB, rowptr, es, N);
  gemm40_kernel<<<nb_g, 320, 0, stream>>>(Hh, W2 + 1 * 5120, zB, zA, N);
  prop40_kernel<<<nb_p, 256, 0, stream>>>(zA, zB, rowptr, es, N);
  gemm40_kernel<<<nb_g, 320, 0, stream>>>(Hh, W2 + 0 * 5120, zB, zA, N);

  // ---- log_softmax ----
  lsm_kernel<<<nb_p, 256, 0, stream>>>(zA, b2, out, N);
}

// Round 3
// 552.153 us; speedup vs baseline: 1.7235x; 1.3001x over previous
//
#include <hip/hip_runtime.h>
#include <hip/hip_bf16.h>
#include <hip/hip_fp16.h>

// ---------------------------------------------------------------------------
// TAGConv x2 (K=3), N=50000, E=800000, 128->128 relu -> 40 logsoftmax
//   Horner: out = y0 + A(y1 + A(y2 + A y3)), y_k = X @ W[k]
//   CSR built with raw weights (int-atomic count only); deg/dis from CSR
//   row-sums (no float atomics); normalize pass folds dis into edge weights.
//   GEMMs via v_mfma_f32_16x16x32_f16 (fp16 in, fp32 acc), weights
//   pre-transposed [col][k]; LDS XOR-swizzled.
//   prop128 gathers fp16 (256B/edge), prop40 gathers fp16 (80B/edge).
// ---------------------------------------------------------------------------

using half8 = __attribute__((ext_vector_type(8))) _Float16;
using f32x4 = __attribute__((ext_vector_type(4))) float;

__global__ void zero_kernel(int* __restrict__ cnt, int n) {
  int i = blockIdx.x * blockDim.x + threadIdx.x;
  if (i < n) cnt[i] = 0;
}

__global__ void count_kernel(const int* __restrict__ ei, int* __restrict__ cnt, int E) {
  int e = blockIdx.x * blockDim.x + threadIdx.x;
  if (e < E) atomicAdd(&cnt[ei[E + e]], 1);
}

// --- 3-phase multiblock exclusive scan: cnt[0..n) -> rowptr[0..n] ---
__global__ __launch_bounds__(512) void scanA_kernel(const int* __restrict__ cnt,
                                                    int* __restrict__ rowptr,
                                                    int* __restrict__ bsum, int n) {
  __shared__ int wsum[8];
  int b = blockIdx.x, t = threadIdx.x, lane = t & 63, wid = t >> 6;
  int i = b * 512 + t;
  int v = (i < n) ? cnt[i] : 0;
  int sv = v;
  #pragma unroll
  for (int off = 1; off < 64; off <<= 1) {
    int x = __shfl_up(sv, off);
    if (lane >= off) sv += x;
  }
  if (lane == 63) wsum[wid] = sv;
  __syncthreads();
  if (t == 0) {
    int s = 0;
    #pragma unroll
    for (int j = 0; j < 8; ++j) { int x = wsum[j]; wsum[j] = s; s += x; }
    bsum[b] = s;
  }
  __syncthreads();
  if (i < n) rowptr[i + 1] = sv + wsum[wid];   // chunk-local inclusive
}

__global__ __launch_bounds__(128) void scanB_kernel(const int* __restrict__ bsum,
                                                    int* __restrict__ bo, int nb) {
  __shared__ int w0tot;
  int t = threadIdx.x, lane = t & 63, wid = t >> 6;
  int v = (t < nb) ? bsum[t] : 0;
  int sv = v;
  #pragma unroll
  for (int off = 1; off < 64; off <<= 1) {
    int x = __shfl_up(sv, off);
    if (lane >= off) sv += x;
  }
  if (t == 63) w0tot = sv;
  __syncthreads();
  int incl = sv + (wid ? w0tot : 0);
  if (t < nb) bo[t] = incl - v;    // exclusive block offset
}

__global__ void scanC_kernel(int* __restrict__ rowptr, const int* __restrict__ bo, int n) {
  int i = blockIdx.x * blockDim.x + threadIdx.x;
  if (i < n) rowptr[i + 1] += bo[i >> 9];
  if (i == 0) rowptr[0] = 0;
}

__global__ void copy_kernel(const int* __restrict__ rowptr, int* __restrict__ cursor, int n) {
  int i = blockIdx.x * blockDim.x + threadIdx.x;
  if (i < n) cursor[i] = rowptr[i];
}

__global__ void scatter_kernel(const int* __restrict__ ei, const float* __restrict__ ew,
                               int* __restrict__ cursor, int2* __restrict__ es, int E) {
  int e = blockIdx.x * blockDim.x + threadIdx.x;
  if (e < E) {
    int s = ei[e];
    int d = ei[E + e];
    int pos = atomicAdd(&cursor[d], 1);
    es[pos] = make_int2(s, __float_as_int(ew[e]));   // raw weight
  }
}

// dis[node] = rsqrt(sum of raw w over CSR row), 0 if empty
__global__ void deg_kernel(const int2* __restrict__ es, const int* __restrict__ rowptr,
                           float* __restrict__ dis, int n) {
  int i = blockIdx.x * blockDim.x + threadIdx.x;
  if (i >= n) return;
  int beg = rowptr[i], end = rowptr[i + 1];
  float s = 0.f;
  for (int e = beg; e < end; ++e) s += __int_as_float(es[e].y);
  dis[i] = (s > 0.f) ? rsqrtf(s) : 0.f;
}

// es[e].w = w_raw * dis[dst] * dis[src]
__global__ void norm_kernel(int2* __restrict__ es, const int* __restrict__ rowptr,
                            const float* __restrict__ dis, int n) {
  int i = blockIdx.x * blockDim.x + threadIdx.x;
  if (i >= n) return;
  int beg = rowptr[i], end = rowptr[i + 1];
  float dn = dis[i];
  for (int e = beg; e < end; ++e) {
    int2 p = es[e];
    float wv = __int_as_float(p.y) * dn * dis[p.x];
    es[e] = make_int2(p.x, __float_as_int(wv));
  }
}

// ---- dtype conversions ----
__global__ void xh_kernel(const float* __restrict__ x, __half* __restrict__ xh, int total4) {
  int i = blockIdx.x * blockDim.x + threadIdx.x;
  if (i < total4) {
    float4 v = ((const float4*)x)[i];
    __half2* o = (__half2*)xh;
    o[i * 2 + 0] = __floats2half2_rn(v.x, v.y);
    o[i * 2 + 1] = __floats2half2_rn(v.z, v.w);
  }
}

// W[s][k][c] (fp32, incols) -> Wt[s][c][k] (fp16, cols padded), k=0..127
__global__ void wt_kernel(const float* __restrict__ W, __half* __restrict__ Wt,
                          int total, int cols, int incols) {
  int i = blockIdx.x * blockDim.x + threadIdx.x;
  if (i >= total) return;
  int kk = i & 127;
  int rem = i >> 7;
  int c = rem % cols;
  int s = rem / cols;
  float v = (c < incols) ? W[(size_t)s * 128 * incols + (size_t)kk * incols + c] : 0.f;
  Wt[i] = __float2half(v);
}

// ---- MFMA GEMMs ----
// Yh[n x 128](fp16) = relu?( Acc? + Xh @ W + bias? ); 64 rows/block, 4 waves
__global__ __launch_bounds__(256) void g128_kernel(const __half* __restrict__ Xh,
                                                   const __half* __restrict__ Wt,
                                                   const float* __restrict__ Acc,
                                                   const float* __restrict__ bias,
                                                   __half* __restrict__ Yh, int n) {
  __shared__ __align__(16) __half sX[64 * 128];
  __shared__ __align__(16) __half sW[128 * 128];
  int t = threadIdx.x;
  int row0 = blockIdx.x * 64;
  for (int c8 = t; c8 < 2048; c8 += 256) {          // W: 128 rows(col-idx) x 16 chunks
    int r = c8 >> 4, ck = c8 & 15;
    half8 v = *(const half8*)&Wt[c8 * 8];
    *(half8*)&sW[(r * 16 + (ck ^ (r & 7))) * 8] = v;
  }
  for (int c8 = t; c8 < 1024; c8 += 256) {          // X: 64 rows x 16 chunks
    int r = c8 >> 4, ck = c8 & 15;
    int gr = row0 + r;
    half8 v = {};
    if (gr < n) v = *(const half8*)&Xh[(size_t)gr * 128 + ck * 8];
    *(half8*)&sX[(r * 16 + (ck ^ (r & 7))) * 8] = v;
  }
  __syncthreads();
  int w = t >> 6, lane = t & 63;
  int lrow = lane & 15, lk = lane >> 4;
  half8 a[4];
  {
    int r = w * 16 + lrow;
    #pragma unroll
    for (int kk = 0; kk < 4; ++kk) {
      int ck = kk * 4 + lk;
      a[kk] = *(const half8*)&sX[(r * 16 + (ck ^ (r & 7))) * 8];
    }
  }
  f32x4 acc[8];
  #pragma unroll
  for (int ct = 0; ct < 8; ++ct) acc[ct] = (f32x4){0.f, 0.f, 0.f, 0.f};
  #pragma unroll
  for (int ct = 0; ct < 8; ++ct) {
    int c = ct * 16 + lrow;
    #pragma unroll
    for (int kk = 0; kk < 4; ++kk) {
      int ck = kk * 4 + lk;
      half8 b = *(const half8*)&sW[(c * 16 + (ck ^ (c & 7))) * 8];
      acc[ct] = __builtin_amdgcn_mfma_f32_16x16x32_f16(a[kk], b, acc[ct], 0, 0, 0);
    }
  }
  int ocol = lane & 15;
  int orow = (lane >> 4) * 4;
  #pragma unroll
  for (int ct = 0; ct < 8; ++ct) {
    int c = ct * 16 + ocol;
    #pragma unroll
    for (int rg = 0; rg < 4; ++rg) {
      int gr = row0 + w * 16 + orow + rg;
      if (gr < n) {
        float v = acc[ct][rg];
        if (Acc) v += Acc[(size_t)gr * 128 + c];
        if (bias) v = fmaxf(v + bias[c], 0.f);
        Yh[(size_t)gr * 128 + c] = __float2half(v);
      }
    }
  }
}

// Z[n x 40] = Acc? + Xh @ W2t ; 64 rows/block; out fp16 (Yh) or fp32 (Yf)
__global__ __launch_bounds__(256) void g40_kernel(const __half* __restrict__ Xh,
                                                  const __half* __restrict__ Wt,
                                                  const float* __restrict__ Acc,
                                                  __half* __restrict__ Yh,
                                                  float* __restrict__ Yf, int n) {
  __shared__ __align__(16) __half sX[64 * 128];
  __shared__ __align__(16) __half sW[48 * 128];
  int t = threadIdx.x;
  int row0 = blockIdx.x * 64;
  for (int c8 = t; c8 < 768; c8 += 256) {           // W: 48 x 16 chunks
    int r = c8 >> 4, ck = c8 & 15;
    half8 v = *(const half8*)&Wt[c8 * 8];
    *(half8*)&sW[(r * 16 + (ck ^ (r & 7))) * 8] = v;
  }
  for (int c8 = t; c8 < 1024; c8 += 256) {
    int r = c8 >> 4, ck = c8 & 15;
    int gr = row0 + r;
    half8 v = {};
    if (gr < n) v = *(const half8*)&Xh[(size_t)gr * 128 + ck * 8];
    *(half8*)&sX[(r * 16 + (ck ^ (r & 7))) * 8] = v;
  }
  __syncthreads();
  int w = t >> 6, lane = t & 63;
  int lrow = lane & 15, lk = lane >> 4;
  half8 a[4];
  {
    int r = w * 16 + lrow;
    #pragma unroll
    for (int kk = 0; kk < 4; ++kk) {
      int ck = kk * 4 + lk;
      a[kk] = *(const half8*)&sX[(r * 16 + (ck ^ (r & 7))) * 8];
    }
  }
  f32x4 acc[3];
  #pragma unroll
  for (int ct = 0; ct < 3; ++ct) acc[ct] = (f32x4){0.f, 0.f, 0.f, 0.f};
  #pragma unroll
  for (int ct = 0; ct < 3; ++ct) {
    int c = ct * 16 + lrow;
    #pragma unroll
    for (int kk = 0; kk < 4; ++kk) {
      int ck = kk * 4 + lk;
      half8 b = *(const half8*)&sW[(c * 16 + (ck ^ (c & 7))) * 8];
      acc[ct] = __builtin_amdgcn_mfma_f32_16x16x32_f16(a[kk], b, acc[ct], 0, 0, 0);
    }
  }
  int ocol = lane & 15;
  int orow = (lane >> 4) * 4;
  #pragma unroll
  for (int ct = 0; ct < 3; ++ct) {
    int c = ct * 16 + ocol;
    if (c >= 40) continue;
    #pragma unroll
    for (int rg = 0; rg < 4; ++rg) {
      int gr = row0 + w * 16 + orow + rg;
      if (gr < n) {
        float v = acc[ct][rg];
        if (Acc) v += Acc[(size_t)gr * 40 + c];
        if (Yh) Yh[(size_t)gr * 40 + c] = __float2half(v);
        else    Yf[(size_t)gr * 40 + c] = v;
      }
    }
  }
}

// P[n x 128](fp32) = A . srch(fp16); one wave/node, lane = half2
__global__ __launch_bounds__(256) void prop128_kernel(const __half* __restrict__ srch,
                                                      float* __restrict__ dstf,
                                                      const int* __restrict__ rowptr,
                                                      const int2* __restrict__ es, int n) {
  int lane = threadIdx.x & 63;
  int node = blockIdx.x * 4 + (threadIdx.x >> 6);
  if (node >= n) return;
  int beg = rowptr[node], end = rowptr[node + 1];
  const __half2* sf = (const __half2*)srch;
  float ax = 0.f, ay = 0.f;
  int e = beg;
  for (; e + 3 < end; e += 4) {
    int2 p0 = es[e], p1 = es[e + 1], p2 = es[e + 2], p3 = es[e + 3];
    float2 v0 = __half22float2(sf[(size_t)p0.x * 64 + lane]);
    float2 v1 = __half22float2(sf[(size_t)p1.x * 64 + lane]);
    float2 v2 = __half22float2(sf[(size_t)p2.x * 64 + lane]);
    float2 v3 = __half22float2(sf[(size_t)p3.x * 64 + lane]);
    float w0 = __int_as_float(p0.y), w1 = __int_as_float(p1.y);
    float w2 = __int_as_float(p2.y), w3 = __int_as_float(p3.y);
    ax += w0 * v0.x; ay += w0 * v0.y;
    ax += w1 * v1.x; ay += w1 * v1.y;
    ax += w2 * v2.x; ay += w2 * v2.y;
    ax += w3 * v3.x; ay += w3 * v3.y;
  }
  for (; e < end; ++e) {
    int2 p = es[e];
    float2 v = __half22float2(sf[(size_t)p.x * 64 + lane]);
    float w = __int_as_float(p.y);
    ax += w * v.x; ay += w * v.y;
  }
  ((float2*)dstf)[(size_t)node * 64 + lane] = make_float2(ax, ay);
}

// P40[n x 40](fp32) = A . srch(fp16, 40-wide); one wave/node, lanes 0..39
__global__ __launch_bounds__(256) void prop40_kernel(const __half* __restrict__ srch,
                                                     float* __restrict__ dstf,
                                                     const int* __restrict__ rowptr,
                                                     const int2* __restrict__ es, int n) {
  int lane = threadIdx.x & 63;
  int node = blockIdx.x * 4 + (threadIdx.x >> 6);
  if (node >= n) return;
  int beg = rowptr[node], end = rowptr[node + 1];
  float acc = 0.f;
  int e = beg;
  for (; e + 3 < end; e += 4) {
    int2 p0 = es[e], p1 = es[e + 1], p2 = es[e + 2], p3 = es[e + 3];
    float v0 = (lane < 40) ? __half2float(srch[(size_t)p0.x * 40 + lane]) : 0.f;
    float v1 = (lane < 40) ? __half2float(srch[(size_t)p1.x * 40 + lane]) : 0.f;
    float v2 = (lane < 40) ? __half2float(srch[(size_t)p2.x * 40 + lane]) : 0.f;
    float v3 = (lane < 40) ? __half2float(srch[(size_t)p3.x * 40 + lane]) : 0.f;
    acc += __int_as_float(p0.y) * v0 + __int_as_float(p1.y) * v1
         + __int_as_float(p2.y) * v2 + __int_as_float(p3.y) * v3;
  }
  for (; e < end; ++e) {
    int2 p = es[e];
    float v = (lane < 40) ? __half2float(srch[(size_t)p.x * 40 + lane]) : 0.f;
    acc += __int_as_float(p.y) * v;
  }
  if (lane < 40) dstf[(size_t)node * 40 + lane] = acc;
}

// out[n x 40] = log_softmax(Z + b2); one wave per node
__global__ __launch_bounds__(256) void lsm_kernel(const float* __restrict__ Z,
                                                  const float* __restrict__ b,
                                                  float* __restrict__ out, int n) {
  int lane = threadIdx.x & 63;
  int node = blockIdx.x * 4 + (threadIdx.x >> 6);
  if (node >= n) return;
  float v = -1e30f;
  if (lane < 40) v = Z[(size_t)node * 40 + lane] + b[lane];
  float m = v;
  #pragma unroll
  for (int off = 32; off; off >>= 1) m = fmaxf(m, __shfl_xor(m, off));
  float ex = (lane < 40) ? __expf(v - m) : 0.f;
  float s = ex;
  #pragma unroll
  for (int off = 32; off; off >>= 1) s += __shfl_xor(s, off);
  if (lane < 40) out[(size_t)node * 40 + lane] = v - m - __logf(s);
}

extern "C" void kernel_launch(void* const* d_in, const int* in_sizes, int n_in,
                              void* d_out, int out_size, void* d_ws, size_t ws_size,
                              hipStream_t stream) {
  const float* x  = (const float*)d_in[0];
  const int*   ei = (const int*)d_in[1];
  const float* ew = (const float*)d_in[2];
  const float* W1 = (const float*)d_in[3];
  const float* b1 = (const float*)d_in[4];
  const float* W2 = (const float*)d_in[5];
  const float* b2 = (const float*)d_in[6];
  float* out = (float*)d_out;

  const int N = in_sizes[0] / 128;   // 50000
  const int E = in_sizes[2];         // 800000
  const int NB_SCAN = (N + 511) / 512;

  char* ws = (char*)d_ws;
  size_t off = 0;
  auto alloc = [&](size_t bytes) -> void* {
    off = (off + 255) & ~(size_t)255;
    void* p = ws + off;
    off += bytes;
    return p;
  };
  float*  dis    = (float*) alloc((size_t)N * 4);
  int*    rowptr = (int*)   alloc((size_t)(N + 1) * 4);
  int*    cnt    = (int*)   alloc((size_t)N * 4);
  int*    cursor = (int*)   alloc((size_t)N * 4);
  int*    bsum   = (int*)   alloc((size_t)NB_SCAN * 4);
  int*    bo     = (int*)   alloc((size_t)NB_SCAN * 4);
  int2*   es     = (int2*)  alloc((size_t)E * 8);
  float*  P      = (float*) alloc((size_t)N * 128 * 4);  // layer1 prop out / layer2 alias
  __half* Hh     = (__half*)alloc((size_t)N * 128 * 2);  // g128 fp16 out (h)
  __half* Xh     = (__half*)alloc((size_t)N * 128 * 2);  // x fp16 (dead after layer1)
  __half* W1t    = (__half*)alloc((size_t)4 * 128 * 128 * 2);
  __half* W2t    = (__half*)alloc((size_t)4 * 48 * 128 * 2);
  float*  P40    = P;                     // N*40 fp32
  float*  Zf     = P + (size_t)N * 40;    // N*40 fp32 (final logits)
  __half* Zh     = Xh;                    // N*40 fp16 (layer2 prop src)
  (void)ws_size; (void)n_in; (void)out_size;

  int nb_n = (N + 255) / 256;
  int nb_e = (E + 255) / 256;
  int nb_g = (N + 63) / 64;
  int nb_p = (N + 3) / 4;

  // ---- graph preprocessing ----
  zero_kernel<<<nb_n, 256, 0, stream>>>(cnt, N);
  count_kernel<<<nb_e, 256, 0, stream>>>(ei, cnt, E);
  scanA_kernel<<<NB_SCAN, 512, 0, stream>>>(cnt, rowptr, bsum, N);
  scanB_kernel<<<1, 128, 0, stream>>>(bsum, bo, NB_SCAN);
  scanC_kernel<<<nb_n, 256, 0, stream>>>(rowptr, bo, N);
  copy_kernel<<<nb_n, 256, 0, stream>>>(rowptr, cursor, N);
  scatter_kernel<<<nb_e, 256, 0, stream>>>(ei, ew, cursor, es, E);
  deg_kernel<<<nb_n, 256, 0, stream>>>(es, rowptr, dis, N);
  norm_kernel<<<nb_n, 256, 0, stream>>>(es, rowptr, dis, N);

  // ---- dtype prep ----
  xh_kernel<<<(N * 32 + 255) / 256, 256, 0, stream>>>(x, Xh, N * 32);
  wt_kernel<<<(4 * 128 * 128 + 255) / 256, 256, 0, stream>>>(W1, W1t, 4 * 128 * 128, 128, 128);
  wt_kernel<<<(4 * 48 * 128 + 255) / 256, 256, 0, stream>>>(W2, W2t, 4 * 48 * 128, 48, 40);

  // ---- layer 1 (Horner, fp16 gathers, MFMA gemms) ----
  g128_kernel<<<nb_g, 256, 0, stream>>>(Xh, W1t + 3 * 16384, nullptr, nullptr, Hh, N);
  prop128_kernel<<<nb_p, 256, 0, stream>>>(Hh, P, rowptr, es, N);
  g128_kernel<<<nb_g, 256, 0, stream>>>(Xh, W1t + 2 * 16384, P, nullptr, Hh, N);
  prop128_kernel<<<nb_p, 256, 0, stream>>>(Hh, P, rowptr, es, N);
  g128_kernel<<<nb_g, 256, 0, stream>>>(Xh, W1t + 1 * 16384, P, nullptr, Hh, N);
  prop128_kernel<<<nb_p, 256, 0, stream>>>(Hh, P, rowptr, es, N);
  g128_kernel<<<nb_g, 256, 0, stream>>>(Xh, W1t + 0 * 16384, P, b1, Hh, N);  // h fp16

  // ---- layer 2 (Horner, 40-wide fp16 gathers) ----
  g40_kernel<<<nb_g, 256, 0, stream>>>(Hh, W2t + 3 * 6144, nullptr, Zh, nullptr, N);
  prop40_kernel<<<nb_p, 256, 0, stream>>>(Zh, P40, rowptr, es, N);
  g40_kernel<<<nb_g, 256, 0, stream>>>(Hh, W2t + 2 * 6144, P40, Zh, nullptr, N);
  prop40_kernel<<<nb_p, 256, 0, stream>>>(Zh, P40, rowptr, es, N);
  g40_kernel<<<nb_g, 256, 0, stream>>>(Hh, W2t + 1 * 6144, P40, Zh, nullptr, N);
  prop40_kernel<<<nb_p, 256, 0, stream>>>(Zh, P40, rowptr, es, N);
  g40_kernel<<<nb_g, 256, 0, stream>>>(Hh, W2t + 0 * 6144, P40, nullptr, Zf, N);

  // ---- log_softmax ----
  lsm_kernel<<<nb_p, 256, 0, stream>>>(Zf, b2, out, N);
}